// Round 1
// baseline (467.653 us; speedup 1.0000x reference)
//
#include <hip/hip_runtime.h>
#include <stdint.h>

// Problem constants (match reference)
#define B_TOT 4096
#define T_LEN 2048
#define D_IN  10
#define OUT_N 30
#define TT    32                       // timesteps per LDS tile
#define NT    (T_LEN/TT)               // 64 tiles
#define SMP_BLK 16                     // samples per block (one 16-lane group each)
#define TILE_FLOATS (TT*SMP_BLK*D_IN)  // 5120 floats = 20 KB per buffer

// async global->LDS, width 4 (per-lane arbitrary global addr, linear LDS dest)
#define GLD4(gptr, lptr) __builtin_amdgcn_global_load_lds( \
    (const __attribute__((address_space(1))) void*)(gptr),  \
    (__attribute__((address_space(3))) void*)(lptr), 4, 0, 0)

// Main LSTM scan: 16 lanes per sample.
// lane layout within a 16-lane group: unit u = (lane>>2)&3, gate type tau = lane&3
// gate row in PyTorch weight layout (i,f,g,o): r = tau*4 + u
__launch_bounds__(256, 1)
__global__ void lstm_scan_kernel(const float* __restrict__ X,
                                 const float* __restrict__ W_ih,
                                 const float* __restrict__ W_hh,
                                 const float* __restrict__ b_ih,
                                 const float* __restrict__ b_hh,
                                 float* __restrict__ hT)
{
    __shared__ float lds[2][TILE_FLOATS];

    const int tid  = threadIdx.x;
    const int lane = tid & 63;
    const int g    = tid >> 4;          // sample within block (0..15)
    const int u    = (tid >> 2) & 3;    // hidden unit
    const int tau  = tid & 3;           // 0=i,1=f,2=g,3=o
    const int r    = tau * 4 + u;       // weight row
    const int w    = tid >> 6;          // wave within block (0..3)

    // per-lane constant weights (all in VGPRs for the whole T loop)
    float wih[10];
    #pragma unroll
    for (int d0 = 0; d0 < 10; ++d0) wih[d0] = W_ih[r*10 + d0];
    const float whh0 = W_hh[r*4+0], whh1 = W_hh[r*4+1],
                whh2 = W_hh[r*4+2], whh3 = W_hh[r*4+3];
    const float bsum = b_ih[r] + b_hh[r];
    // branchless activation: a = fma(k1, rcp(1 + exp2(mneg*x)), k0)
    //   sigmoid: mneg=-log2e,  k1=1, k0=0
    //   tanh:    mneg=-2log2e, k1=2, k0=-1
    const float mneg = (tau == 2) ? -2.8853900817779268f : -1.4426950408889634f;
    const float k1   = (tau == 2) ? 2.0f : 1.0f;
    const float k0   = (tau == 2) ? -1.0f : 0.0f;

    // staging: 80 width-4 instructions per tile per block, 20 per wave.
    // LDS float index p = (t*16 + s)*10 + d  (t within tile, s sample-in-block)
    uint32_t voff[20];
    const uint32_t samp0 = (uint32_t)blockIdx.x * SMP_BLK;
    #pragma unroll
    for (int kk = 0; kk < 20; ++kk) {
        int p   = (w*20 + kk)*64 + lane;
        int t   = p / 160;              // D_IN*SMP_BLK = 160
        int rem = p - t*160;
        int s   = rem / 10;
        int d0  = rem - s*10;
        voff[kk] = (samp0 + (uint32_t)s) * (uint32_t)(T_LEN*D_IN*4)
                 + (uint32_t)(t*40 + d0*4);
    }
    const char* Xc = (const char*)X;

    // prologue: stage tile 0 into buf 0
    #pragma unroll
    for (int kk = 0; kk < 20; ++kk)
        GLD4(Xc + voff[kk], &lds[0][(w*20+kk)*64]);
    __syncthreads();   // compiler emits s_waitcnt vmcnt(0) before s_barrier

    // shuffle source lane bases (absolute within the 64-lane wave)
    const int qb = lane & 60;           // quad base: acts i,f,g,o of my unit
    const int gb = lane & 48;           // 16-group base: h of units 0..3 at +0,+4,+8,+12

    float h0=0.f, h1=0.f, h2=0.f, h3=0.f, c=0.f, hown=0.f;

    for (int tile = 0; tile < NT; ++tile) {
        const int cur = tile & 1;
        if (tile + 1 < NT) {
            const uint32_t add = (uint32_t)(tile+1) * (uint32_t)(TT*D_IN*4);
            #pragma unroll
            for (int kk = 0; kk < 20; ++kk)
                GLD4(Xc + (voff[kk] + add), &lds[cur^1][(w*20+kk)*64]);
        }
        // broadcast reads: all 16 lanes of group g read the same 40B row
        const float2* xp = (const float2*)((const char*)&lds[cur][0] + g*40);
        #pragma unroll 4
        for (int t = 0; t < TT; ++t) {
            float2 x01 = xp[t*80+0], x23 = xp[t*80+1], x45 = xp[t*80+2],
                   x67 = xp[t*80+3], x89 = xp[t*80+4];
            float acc = bsum;                       // x-projection (off critical path)
            acc = fmaf(wih[0], x01.x, acc); acc = fmaf(wih[1], x01.y, acc);
            acc = fmaf(wih[2], x23.x, acc); acc = fmaf(wih[3], x23.y, acc);
            acc = fmaf(wih[4], x45.x, acc); acc = fmaf(wih[5], x45.y, acc);
            acc = fmaf(wih[6], x67.x, acc); acc = fmaf(wih[7], x67.y, acc);
            acc = fmaf(wih[8], x89.x, acc); acc = fmaf(wih[9], x89.y, acc);
            acc = fmaf(whh0, h0, acc); acc = fmaf(whh1, h1, acc);  // recurrent part
            acc = fmaf(whh2, h2, acc); acc = fmaf(whh3, h3, acc);
            // activation (sigmoid or tanh per lane type)
            float e = exp2f(acc * mneg);
            float a = fmaf(k1, __builtin_amdgcn_rcpf(1.0f + e), k0);
            // gather the 4 gate activations of my unit (quad-local)
            float gi = __shfl(a, qb + 0);
            float gf = __shfl(a, qb + 1);
            float gg = __shfl(a, qb + 2);   // already tanh'd
            float go = __shfl(a, qb + 3);
            // cell/hidden update (computed redundantly by all 4 lanes of the quad)
            c = fmaf(gf, c, gi * gg);
            float et = exp2f(c * -2.8853900817779268f);
            float tc = fmaf(2.0f, __builtin_amdgcn_rcpf(1.0f + et), -1.0f);
            hown = go * tc;
            // broadcast h_0..h_3 to every lane of the 16-group (for next step's dot)
            h0 = __shfl(hown, gb + 0);
            h1 = __shfl(hown, gb + 4);
            h2 = __shfl(hown, gb + 8);
            h3 = __shfl(hown, gb + 12);
        }
        __syncthreads();  // drains this tile's prefetch + protects buffer swap
    }

    if (tau == 0) hT[(samp0 + g)*4 + u] = hown;
}

// Head: logits = hT @ W_out^T + b_out, then softmax. One thread per sample.
__global__ void head_kernel(const float* __restrict__ hT,
                            const float* __restrict__ W_out,
                            const float* __restrict__ b_out,
                            float* __restrict__ out)
{
    int b = blockIdx.x * blockDim.x + threadIdx.x;
    if (b >= B_TOT) return;
    float4 h = ((const float4*)hT)[b];
    float lg[OUT_N];
    float m = -1e30f;
    #pragma unroll
    for (int o = 0; o < OUT_N; ++o) {
        float v = b_out[o];
        v = fmaf(W_out[o*4+0], h.x, v);
        v = fmaf(W_out[o*4+1], h.y, v);
        v = fmaf(W_out[o*4+2], h.z, v);
        v = fmaf(W_out[o*4+3], h.w, v);
        lg[o] = v;
        m = fmaxf(m, v);
    }
    float s = 0.f;
    #pragma unroll
    for (int o = 0; o < OUT_N; ++o) {
        float e = exp2f((lg[o] - m) * 1.4426950408889634f);
        lg[o] = e;
        s += e;
    }
    float rs = 1.0f / s;
    #pragma unroll
    for (int o = 0; o < OUT_N; ++o) out[(size_t)b*OUT_N + o] = lg[o] * rs;
}

extern "C" void kernel_launch(void* const* d_in, const int* in_sizes, int n_in,
                              void* d_out, int out_size, void* d_ws, size_t ws_size,
                              hipStream_t stream)
{
    const float* X     = (const float*)d_in[0];
    const float* W_ih  = (const float*)d_in[1];
    const float* W_hh  = (const float*)d_in[2];
    const float* b_ih  = (const float*)d_in[3];
    const float* b_hh  = (const float*)d_in[4];
    const float* W_out = (const float*)d_in[5];
    const float* b_out = (const float*)d_in[6];
    float* out = (float*)d_out;
    float* hTs = (float*)d_ws;   // 4096*4 floats = 64 KB scratch

    lstm_scan_kernel<<<B_TOT/SMP_BLK, 256, 0, stream>>>(X, W_ih, W_hh, b_ih, b_hh, hTs);
    head_kernel<<<B_TOT/256, 256, 0, stream>>>(hTs, W_out, b_out, out);
}

// Round 2
// 342.036 us; speedup vs baseline: 1.3673x; 1.3673x over previous
//
#include <hip/hip_runtime.h>
#include <stdint.h>

// Problem constants (match reference)
#define B_TOT 4096
#define T_LEN 2048
#define D_IN  10
#define OUT_N 30
#define TT    32                       // timesteps per LDS tile
#define NT    (T_LEN/TT)               // 64 tiles
#define SMP_BLK 16                     // samples per block (one 16-lane group each)
#define TILE_FLOATS (TT*SMP_BLK*D_IN)  // 5120 floats = 20 KB per buffer

// async global->LDS, width 4 (per-lane arbitrary global addr, linear LDS dest)
#define GLD4(gptr, lptr) __builtin_amdgcn_global_load_lds( \
    (const __attribute__((address_space(1))) void*)(gptr),  \
    (__attribute__((address_space(3))) void*)(lptr), 4, 0, 0)

// DPP cross-lane move (VALU pipe — no LDS latency, ctrl is an immediate)
// quad_perm broadcast k: ctrl = k*0x55. row_ror:N: ctrl = 0x120+N.
// Semantics (GCN/CDNA): row_ror:N -> dest lane i receives src lane (i-N) mod 16
// (same direction as row_shr used in AMD DPP prefix-sum examples).
template<int CTRL>
__device__ __forceinline__ float dppf(float x) {
    return __int_as_float(
        __builtin_amdgcn_mov_dpp(__float_as_int(x), CTRL, 0xF, 0xF, true));
}

// Main LSTM scan: 16 lanes per sample.
// lane layout within a 16-lane group (one DPP row): unit u = (lane>>2)&3,
// gate type tau = lane&3. Weight row (PyTorch i,f,g,o order): r = tau*4 + u
__launch_bounds__(256, 1)
__global__ void lstm_scan_kernel(const float* __restrict__ X,
                                 const float* __restrict__ W_ih,
                                 const float* __restrict__ W_hh,
                                 const float* __restrict__ b_ih,
                                 const float* __restrict__ b_hh,
                                 float* __restrict__ hT)
{
    __shared__ float lds[2][TILE_FLOATS];

    const int tid  = threadIdx.x;
    const int lane = tid & 63;
    const int g    = tid >> 4;          // sample within block (0..15)
    const int u    = (tid >> 2) & 3;    // hidden unit
    const int tau  = tid & 3;           // 0=i,1=f,2=g,3=o
    const int r    = tau * 4 + u;       // weight row
    const int w    = tid >> 6;          // wave within block (0..3)

    // branchless activation: a = fma(k1, rcp(1 + exp2(acc)), k0), where the
    // pre-activation is accumulated PRE-SCALED by mneg:
    //   sigmoid: mneg=-log2e,  k1=1, k0=0   ->  1/(1+exp(-x))
    //   tanh:    mneg=-2log2e, k1=2, k0=-1  ->  2/(1+exp(-2x)) - 1
    const float mneg = (tau == 2) ? -2.8853900817779268f : -1.4426950408889634f;
    const float k1   = (tau == 2) ? 2.0f : 1.0f;
    const float k0   = (tau == 2) ? -1.0f : 0.0f;

    // per-lane constant weights, pre-scaled by mneg (all VGPR-resident)
    float wih[10];
    #pragma unroll
    for (int d0 = 0; d0 < 10; ++d0) wih[d0] = W_ih[r*10 + d0] * mneg;
    // rotated W_hh columns to match row_ror data placement:
    //   own h (no DPP)   -> column u
    //   row_ror:4  value -> h of unit (u-1)&3 -> column (u+3)&3
    //   row_ror:8  value -> h of unit (u-2)&3 -> column (u+2)&3
    //   row_ror:12 value -> h of unit (u+1)&3 -> column (u+1)&3
    const float whhA = W_hh[r*4 +  u        ] * mneg;
    const float whhB = W_hh[r*4 + ((u+3)&3)] * mneg;
    const float whhC = W_hh[r*4 + ((u+2)&3)] * mneg;
    const float whhD = W_hh[r*4 + ((u+1)&3)] * mneg;
    const float bsum = (b_ih[r] + b_hh[r]) * mneg;

    // staging: 80 width-4 instructions per tile per block, 20 per wave.
    // LDS float index p = (t*16 + s)*10 + d  (t within tile, s sample-in-block)
    uint32_t voff[20];
    const uint32_t samp0 = (uint32_t)blockIdx.x * SMP_BLK;
    #pragma unroll
    for (int kk = 0; kk < 20; ++kk) {
        int p   = (w*20 + kk)*64 + lane;
        int t   = p / 160;              // D_IN*SMP_BLK = 160
        int rem = p - t*160;
        int s   = rem / 10;
        int d0  = rem - s*10;
        voff[kk] = (samp0 + (uint32_t)s) * (uint32_t)(T_LEN*D_IN*4)
                 + (uint32_t)(t*40 + d0*4);
    }
    const char* Xc = (const char*)X;

    // prologue: stage tile 0 into buf 0
    #pragma unroll
    for (int kk = 0; kk < 20; ++kk)
        GLD4(Xc + voff[kk], &lds[0][(w*20+kk)*64]);
    __syncthreads();   // compiler emits s_waitcnt vmcnt(0) before s_barrier

    float c = 0.f, hown = 0.f;

    for (int tile = 0; tile < NT; ++tile) {
        const int cur = tile & 1;
        if (tile + 1 < NT) {
            const uint32_t add = (uint32_t)(tile+1) * (uint32_t)(TT*D_IN*4);
            #pragma unroll
            for (int kk = 0; kk < 20; ++kk)
                GLD4(Xc + (voff[kk] + add), &lds[cur^1][(w*20+kk)*64]);
        }
        // broadcast reads: all 16 lanes of group g read the same 40B row
        const float2* xp = (const float2*)((const char*)&lds[cur][0] + g*40);
        #pragma unroll 4
        for (int t = 0; t < TT; ++t) {
            float2 x01 = xp[t*80+0], x23 = xp[t*80+1], x45 = xp[t*80+2],
                   x67 = xp[t*80+3], x89 = xp[t*80+4];
            // x-projection + bias (off the critical chain)
            float acc = bsum;
            acc = fmaf(wih[0], x01.x, acc); acc = fmaf(wih[1], x01.y, acc);
            acc = fmaf(wih[2], x23.x, acc); acc = fmaf(wih[3], x23.y, acc);
            acc = fmaf(wih[4], x45.x, acc); acc = fmaf(wih[5], x45.y, acc);
            acc = fmaf(wih[6], x67.x, acc); acc = fmaf(wih[7], x67.y, acc);
            acc = fmaf(wih[8], x89.x, acc); acc = fmaf(wih[9], x89.y, acc);
            // recurrent part: h of the other 3 units via DPP row rotates
            float hB = dppf<0x124>(hown);   // row_ror:4  -> h[(u-1)&3]
            float hC = dppf<0x128>(hown);   // row_ror:8  -> h[(u-2)&3]
            float hD = dppf<0x12C>(hown);   // row_ror:12 -> h[(u+1)&3]
            float u1 = fmaf(whhA, hown, acc);
            float u2 = fmaf(whhC, hC, whhD * hD);
            acc = fmaf(whhB, hB, u1) + u2;
            // activation (sigmoid or tanh per lane type); acc is pre-scaled
            float e = exp2f(acc);
            float a = fmaf(k1, __builtin_amdgcn_rcpf(1.0f + e), k0);
            // gather the 4 gate activations of my unit (quad_perm broadcasts)
            float gi = dppf<0x00>(a);
            float gf = dppf<0x55>(a);
            float gg = dppf<0xAA>(a);   // already tanh'd
            float go = dppf<0xFF>(a);
            // cell/hidden update (redundant across the quad)
            c = fmaf(gf, c, gi * gg);
            float et = exp2f(c * -2.8853900817779268f);
            float tc = fmaf(2.0f, __builtin_amdgcn_rcpf(1.0f + et), -1.0f);
            hown = go * tc;
        }
        __syncthreads();  // drains this tile's prefetch + protects buffer swap
    }

    if (tau == 0) hT[(samp0 + g)*4 + u] = hown;
}

// Head: logits = hT @ W_out^T + b_out, then softmax. One thread per sample.
__global__ void head_kernel(const float* __restrict__ hT,
                            const float* __restrict__ W_out,
                            const float* __restrict__ b_out,
                            float* __restrict__ out)
{
    int b = blockIdx.x * blockDim.x + threadIdx.x;
    if (b >= B_TOT) return;
    float4 h = ((const float4*)hT)[b];
    float lg[OUT_N];
    float m = -1e30f;
    #pragma unroll
    for (int o = 0; o < OUT_N; ++o) {
        float v = b_out[o];
        v = fmaf(W_out[o*4+0], h.x, v);
        v = fmaf(W_out[o*4+1], h.y, v);
        v = fmaf(W_out[o*4+2], h.z, v);
        v = fmaf(W_out[o*4+3], h.w, v);
        lg[o] = v;
        m = fmaxf(m, v);
    }
    float s = 0.f;
    #pragma unroll
    for (int o = 0; o < OUT_N; ++o) {
        float e = exp2f((lg[o] - m) * 1.4426950408889634f);
        lg[o] = e;
        s += e;
    }
    float rs = 1.0f / s;
    #pragma unroll
    for (int o = 0; o < OUT_N; ++o) out[(size_t)b*OUT_N + o] = lg[o] * rs;
}

extern "C" void kernel_launch(void* const* d_in, const int* in_sizes, int n_in,
                              void* d_out, int out_size, void* d_ws, size_t ws_size,
                              hipStream_t stream)
{
    const float* X     = (const float*)d_in[0];
    const float* W_ih  = (const float*)d_in[1];
    const float* W_hh  = (const float*)d_in[2];
    const float* b_ih  = (const float*)d_in[3];
    const float* b_hh  = (const float*)d_in[4];
    const float* W_out = (const float*)d_in[5];
    const float* b_out = (const float*)d_in[6];
    float* out = (float*)d_out;
    float* hTs = (float*)d_ws;   // 4096*4 floats = 64 KB scratch

    lstm_scan_kernel<<<B_TOT/SMP_BLK, 256, 0, stream>>>(X, W_ih, W_hh, b_ih, b_hh, hTs);
    head_kernel<<<B_TOT/256, 256, 0, stream>>>(hTs, W_out, b_out, out);
}

// Round 3
// 247.117 us; speedup vs baseline: 1.8924x; 1.3841x over previous
//
#include <hip/hip_runtime.h>
#include <stdint.h>

// Problem constants (match reference)
#define B_TOT 4096
#define T_LEN 2048
#define D_IN  10
#define OUT_N 30
#define TT    64                       // timesteps per LDS tile
#define NT    (T_LEN/TT)               // 32 tiles
#define SMP_BLK 16                     // samples per block (one 16-lane group each)
#define TILE_FLOATS (TT*SMP_BLK*D_IN)  // 10240 floats = 40 KB per buffer
#define NLD   (TILE_FLOATS/(4*64))     // global_load_lds per wave per tile = 40

// async global->LDS, width 4 (per-lane arbitrary global addr, linear LDS dest)
#define GLD4(gptr, lptr) __builtin_amdgcn_global_load_lds( \
    (const __attribute__((address_space(1))) void*)(gptr),  \
    (__attribute__((address_space(3))) void*)(lptr), 4, 0, 0)

// DPP cross-lane move (VALU pipe). quad_perm broadcast k: ctrl=k*0x55.
// row_ror:N: ctrl=0x120+N -> dest lane i receives src lane (i-N) mod 16.
template<int CTRL>
__device__ __forceinline__ float dppf(float x) {
    return __int_as_float(
        __builtin_amdgcn_mov_dpp(__float_as_int(x), CTRL, 0xF, 0xF, true));
}

// raw v_exp_f32 (2^x) — avoid libm exp2f's range-fixup instructions
__device__ __forceinline__ float fast_exp2(float x) {
#if __has_builtin(__builtin_amdgcn_exp2f)
    return __builtin_amdgcn_exp2f(x);
#else
    float r; asm("v_exp_f32 %0, %1" : "=v"(r) : "v"(x)); return r;
#endif
}

// Main LSTM scan: 16 lanes per sample.
// lane layout within a 16-lane group (one DPP row): unit u=(lane>>2)&3,
// gate type tau=lane&3. Weight row (PyTorch i,f,g,o order): r = tau*4+u.
// State kept pre-scaled: cs = ktanh*c with ktanh=-2*log2(e), so tanh(c) =
// 2*rcp(1+exp2(cs)) - 1 with no multiply on the chain.
__launch_bounds__(256, 1)
__global__ void lstm_scan_kernel(const float* __restrict__ X,
                                 const float* __restrict__ W_ih,
                                 const float* __restrict__ W_hh,
                                 const float* __restrict__ b_ih,
                                 const float* __restrict__ b_hh,
                                 float* __restrict__ hT)
{
    __shared__ float lds[2][TILE_FLOATS];

    const int tid  = threadIdx.x;
    const int lane = tid & 63;
    const int g    = tid >> 4;          // sample within block (0..15)
    const int u    = (tid >> 2) & 3;    // hidden unit
    const int tau  = tid & 3;           // 0=i,1=f,2=g,3=o
    const int r    = tau * 4 + u;       // weight row
    const int w    = tid >> 6;          // wave within block (0..3)

    const float KT = -2.8853900817779268f;   // -2*log2(e)
    const float KS = -1.4426950408889634f;   // -log2(e)
    // pre-activation accumulated PRE-SCALED by mneg; a = fma(k1, rcp(1+exp2(acc)), k0)
    //   tau=0 (i): a = KT*sigmoid  (folds the cs-scale into gi)
    //   tau=1 (f): a = sigmoid
    //   tau=2 (g): a = tanh
    //   tau=3 (o): a = 2*sigmoid   (folds the post-rcp doubling of tanh(c))
    const float mneg = (tau == 2) ? KT : KS;
    const float k1   = (tau == 0) ? KT : ((tau == 1) ? 1.0f : 2.0f);
    const float k0   = (tau == 2) ? -1.0f : 0.0f;

    // per-lane constant weights, pre-scaled by mneg (all VGPR-resident)
    float wih[10];
    #pragma unroll
    for (int d0 = 0; d0 < 10; ++d0) wih[d0] = W_ih[r*10 + d0] * mneg;
    // rotated W_hh columns to match row_ror data placement:
    //   own h -> col u; ror:4 -> h[(u-1)&3] -> col (u+3)&3;
    //   ror:8 -> col (u+2)&3; ror:12 -> col (u+1)&3
    const float whhA = W_hh[r*4 +  u        ] * mneg;
    const float whhB = W_hh[r*4 + ((u+3)&3)] * mneg;
    const float whhC = W_hh[r*4 + ((u+2)&3)] * mneg;
    const float whhD = W_hh[r*4 + ((u+1)&3)] * mneg;
    const float bsum = (b_ih[r] + b_hh[r]) * mneg;

    // staging offsets: LDS float index p = (t*16 + s)*10 + d
    uint32_t voff[NLD];
    const uint32_t samp0 = (uint32_t)blockIdx.x * SMP_BLK;
    #pragma unroll
    for (int kk = 0; kk < NLD; ++kk) {
        int p   = (w*NLD + kk)*64 + lane;
        int t   = p / 160;              // D_IN*SMP_BLK = 160
        int rem = p - t*160;
        int s   = rem / 10;
        int d0  = rem - s*10;
        voff[kk] = (samp0 + (uint32_t)s) * (uint32_t)(T_LEN*D_IN*4)
                 + (uint32_t)(t*40 + d0*4);
    }
    const char* Xc = (const char*)X;

    // prologue: stage tile 0 into buf 0
    #pragma unroll
    for (int kk = 0; kk < NLD; ++kk)
        GLD4(Xc + voff[kk], &lds[0][(w*NLD+kk)*64]);
    __syncthreads();

    float cs = 0.f, hown = 0.f;

    for (int tile = 0; tile < NT; ++tile) {
        const int cur = tile & 1;
        if (tile + 1 < NT) {
            const uint32_t add = (uint32_t)(tile+1) * (uint32_t)(TT*D_IN*4);
            #pragma unroll
            for (int kk = 0; kk < NLD; ++kk)
                GLD4(Xc + (voff[kk] + add), &lds[cur^1][(w*NLD+kk)*64]);
        }
        // broadcast reads: all 16 lanes of group g read the same 40B row.
        // step t at float2 index t*80 (+k), 8B-aligned.
        const float2* xp = (const float2*)((const char*)&lds[cur][0] + g*40);

        // pipeline preload: x(1) regs and xacc(0)
        float2 xB[5];
        #pragma unroll
        for (int k = 0; k < 5; ++k) xB[k] = xp[80 + k];
        float xaccA;
        {
            float2 x0 = xp[0], x1 = xp[1], x2 = xp[2], x3 = xp[3], x4 = xp[4];
            float acc = bsum;
            acc = fmaf(wih[0], x0.x, acc); acc = fmaf(wih[1], x0.y, acc);
            acc = fmaf(wih[2], x1.x, acc); acc = fmaf(wih[3], x1.y, acc);
            acc = fmaf(wih[4], x2.x, acc); acc = fmaf(wih[5], x2.y, acc);
            acc = fmaf(wih[6], x3.x, acc); acc = fmaf(wih[7], x3.y, acc);
            acc = fmaf(wih[8], x4.x, acc); acc = fmaf(wih[9], x4.y, acc);
            xaccA = acc;
        }

        #pragma unroll
        for (int t = 0; t < TT; ++t) {
            // issue loads for x(t+2) — consumed one full iteration later
            float2 xN[5];
            if (t + 2 < TT) {
                #pragma unroll
                for (int k = 0; k < 5; ++k) xN[k] = xp[(t+2)*80 + k];
            }
            // x-projection for step t+1 (independent: fills chain stalls)
            float xaccB = 0.f;
            if (t + 1 < TT) {
                float acc = bsum;
                acc = fmaf(wih[0], xB[0].x, acc); acc = fmaf(wih[1], xB[0].y, acc);
                acc = fmaf(wih[2], xB[1].x, acc); acc = fmaf(wih[3], xB[1].y, acc);
                acc = fmaf(wih[4], xB[2].x, acc); acc = fmaf(wih[5], xB[2].y, acc);
                acc = fmaf(wih[6], xB[3].x, acc); acc = fmaf(wih[7], xB[3].y, acc);
                acc = fmaf(wih[8], xB[4].x, acc); acc = fmaf(wih[9], xB[4].y, acc);
                xaccB = acc;
            }
            // ---- serial chain for step t ----
            float hB = dppf<0x124>(hown);   // h[(u-1)&3]
            float hC = dppf<0x128>(hown);   // h[(u-2)&3]
            float hD = dppf<0x12C>(hown);   // h[(u+1)&3]
            float u1 = fmaf(whhA, hown, xaccA);
            float acc = fmaf(whhB, hB, u1) + fmaf(whhD, hD, whhC * hC);
            float e  = fast_exp2(acc);
            float a  = fmaf(k1, __builtin_amdgcn_rcpf(1.0f + e), k0);
            float gi = dppf<0x00>(a);       // KT*sigmoid(i)
            float gf = dppf<0x55>(a);       // sigmoid(f)
            float gg = dppf<0xAA>(a);       // tanh(g)
            float go = dppf<0xFF>(a);       // 2*sigmoid(o)
            float mgo = -0.5f * go;         // off-chain
            cs = fmaf(gf, cs, gi * gg);     // cs = KT * c
            float e2 = fast_exp2(cs);
            float r2 = __builtin_amdgcn_rcpf(1.0f + e2);
            hown = fmaf(go, r2, mgo);       // = sigmoid(o)*tanh(c)
            // rotate pipeline
            #pragma unroll
            for (int k = 0; k < 5; ++k) xB[k] = xN[k];
            xaccA = xaccB;
        }
        __syncthreads();  // drains next-tile prefetch + protects buffer swap
    }

    if (tau == 0) hT[(samp0 + g)*4 + u] = hown;
}

// Head: logits = hT @ W_out^T + b_out, then softmax. One thread per sample.
__global__ void head_kernel(const float* __restrict__ hT,
                            const float* __restrict__ W_out,
                            const float* __restrict__ b_out,
                            float* __restrict__ out)
{
    int b = blockIdx.x * blockDim.x + threadIdx.x;
    if (b >= B_TOT) return;
    float4 h = ((const float4*)hT)[b];
    float lg[OUT_N];
    float m = -1e30f;
    #pragma unroll
    for (int o = 0; o < OUT_N; ++o) {
        float v = b_out[o];
        v = fmaf(W_out[o*4+0], h.x, v);
        v = fmaf(W_out[o*4+1], h.y, v);
        v = fmaf(W_out[o*4+2], h.z, v);
        v = fmaf(W_out[o*4+3], h.w, v);
        lg[o] = v;
        m = fmaxf(m, v);
    }
    float s = 0.f;
    #pragma unroll
    for (int o = 0; o < OUT_N; ++o) {
        float e = fast_exp2((lg[o] - m) * 1.4426950408889634f);
        lg[o] = e;
        s += e;
    }
    float rs = 1.0f / s;
    #pragma unroll
    for (int o = 0; o < OUT_N; ++o) out[(size_t)b*OUT_N + o] = lg[o] * rs;
}

extern "C" void kernel_launch(void* const* d_in, const int* in_sizes, int n_in,
                              void* d_out, int out_size, void* d_ws, size_t ws_size,
                              hipStream_t stream)
{
    const float* X     = (const float*)d_in[0];
    const float* W_ih  = (const float*)d_in[1];
    const float* W_hh  = (const float*)d_in[2];
    const float* b_ih  = (const float*)d_in[3];
    const float* b_hh  = (const float*)d_in[4];
    const float* W_out = (const float*)d_in[5];
    const float* b_out = (const float*)d_in[6];
    float* out = (float*)d_out;
    float* hTs = (float*)d_ws;   // 4096*4 floats = 64 KB scratch

    lstm_scan_kernel<<<B_TOT/SMP_BLK, 256, 0, stream>>>(X, W_ih, W_hh, b_ih, b_hh, hTs);
    head_kernel<<<B_TOT/256, 256, 0, stream>>>(hTs, W_out, b_out, out);
}